// Round 1
// baseline (10311.735 us; speedup 1.0000x reference)
//
#include <hip/hip_runtime.h>

typedef unsigned short u16;
typedef __attribute__((ext_vector_type(8))) short short8;
typedef __attribute__((ext_vector_type(4))) float floatx4;

#define B_   256
#define T_   512
#define E_   512
#define H_   1024
#define G4H  4096
#define KCAT 1536
#define M_   1024

__device__ __forceinline__ u16 f2bf(float f) {
    union { float f; unsigned u; } v; v.f = f;
    unsigned r = (v.u + 0x7fffu + ((v.u >> 16) & 1u)) >> 16;
    return (u16)r;
}
__device__ __forceinline__ float sigf(float x) {
    return __fdividef(1.0f, 1.0f + __expf(-x));
}
__device__ __forceinline__ float tanh_f(float x) {
    return 1.0f - __fdividef(2.0f, __expf(2.0f * x) + 1.0f);
}

// ---------------- prep kernels ----------------

__global__ void prep_emb(const int* __restrict__ x, const float* __restrict__ tab,
                         u16* __restrict__ emb) {
    int idx = (blockIdx.x * 256 + threadIdx.x) * 4;   // elem in [0, B*T*E)
    int row = idx >> 9;                               // / E_
    int e   = idx & 511;
    int xv  = x[row];
    float4 v = *(const float4*)(tab + (size_t)xv * E_ + e);
    ushort4 o; o.x = f2bf(v.x); o.y = f2bf(v.y); o.z = f2bf(v.z); o.w = f2bf(v.w);
    *(ushort4*)(emb + idx) = o;
}

__global__ void prep_wcat(const float* __restrict__ Whh, const float* __restrict__ Wih,
                          u16* __restrict__ wcat) {
    int idx = (blockIdx.x * 256 + threadIdx.x) * 4;   // [0, 4096*1536)
    int g = idx / KCAT;
    int k = idx - g * KCAT;
    const float* src = (k < H_) ? (Whh + (size_t)g * H_ + k)
                                : (Wih + (size_t)g * E_ + (k - H_));
    float4 v = *(const float4*)src;
    ushort4 o; o.x = f2bf(v.x); o.y = f2bf(v.y); o.z = f2bf(v.z); o.w = f2bf(v.w);
    *(ushort4*)(wcat + idx) = o;
}

__global__ void prep_fc1w(const float* __restrict__ src, u16* __restrict__ dst) {
    int idx = (blockIdx.x * 256 + threadIdx.x) * 4;   // [0, 1024*1024)
    float4 v = *(const float4*)(src + idx);
    ushort4 o; o.x = f2bf(v.x); o.y = f2bf(v.y); o.z = f2bf(v.z); o.w = f2bf(v.w);
    *(ushort4*)(dst + idx) = o;
}

__global__ void prep_bias(const float* __restrict__ bih, const float* __restrict__ bhh,
                          float* __restrict__ bias) {
    int i = blockIdx.x * 256 + threadIdx.x;           // [0, 4096)
    bias[i] = bih[i] + bhh[i];
}

__global__ void prep_state(const float* __restrict__ h0, const float* __restrict__ c0,
                           u16* __restrict__ hbuf0, float* __restrict__ cbuf) {
    int i = blockIdx.x * 256 + threadIdx.x;           // [0, B*H)
    hbuf0[i] = f2bf(h0[i]);
    cbuf[i]  = c0[i];
}

// ---------------- LSTM step ----------------
// grid (64, 4): x = col-group (16 h-cols -> 64 gate cols across i,f,g,o), y = batch-group (64 rows)
// gates = [h | emb_t] @ Wcat^T   (K = 1536), bf16 MFMA 16x16x32, 64x64 tile, BK=64

__global__ __launch_bounds__(256) void lstm_step(
    const u16* __restrict__ h_in, u16* __restrict__ h_out,
    float* __restrict__ c_buf, const u16* __restrict__ emb,
    const u16* __restrict__ wcat, const float* __restrict__ bias,
    const int* __restrict__ x_index, float* __restrict__ hn, int t)
{
    __shared__ __align__(16) u16 Al[64 * 72];   // [row][9 chunks pad][8 bf16]
    __shared__ __align__(16) u16 Bl[64 * 72];

    const int tid = threadIdx.x;
    const int rowbase = blockIdx.y * 64;
    const int j0 = blockIdx.x * 16;

    floatx4 acc[4] = {{0,0,0,0},{0,0,0,0},{0,0,0,0},{0,0,0,0}};

    const int w = tid >> 6;
    const int lane = tid & 63;
    const int lr = lane & 15;   // A row-in-tile / B col-in-tile
    const int lk = lane >> 4;   // k quad

    for (int s = 0; s < KCAT / 64; ++s) {
        const int k0 = s * 64;
        #pragma unroll
        for (int cc = 0; cc < 2; ++cc) {
            int c = tid + cc * 256;
            int row = c >> 3;
            int kg  = c & 7;
            int kglob = k0 + kg * 8;
            const u16* asrc = (kglob < H_)
                ? (h_in + (size_t)(rowbase + row) * H_ + kglob)
                : (emb + ((size_t)(rowbase + row) * T_ + t) * E_ + (kglob - H_));
            *(uint4*)&Al[(row * 9 + kg) * 8] = *(const uint4*)asrc;
            int q = row >> 4, jj = row & 15;
            int gcol = q * H_ + j0 + jj;
            *(uint4*)&Bl[(row * 9 + kg) * 8] =
                *(const uint4*)(wcat + (size_t)gcol * KCAT + kglob);
        }
        __syncthreads();
        #pragma unroll
        for (int ks = 0; ks < 2; ++ks) {
            short8 a = *(const short8*)&Al[((16 * w + lr) * 9 + ks * 4 + lk) * 8];
            #pragma unroll
            for (int q = 0; q < 4; ++q) {
                short8 b = *(const short8*)&Bl[((q * 16 + lr) * 9 + ks * 4 + lk) * 8];
                acc[q] = __builtin_amdgcn_mfma_f32_16x16x32_bf16(a, b, acc[q], 0, 0, 0);
            }
        }
        __syncthreads();
    }

    // fused elementwise epilogue: lane owns (4 rows) x (1 h-col)
    const int jglob = j0 + lr;
    const float b_i = bias[jglob];
    const float b_f = bias[H_ + jglob];
    const float b_g = bias[2 * H_ + jglob];
    const float b_o = bias[3 * H_ + jglob];
    #pragma unroll
    for (int r = 0; r < 4; ++r) {
        int brow = rowbase + 16 * w + lk * 4 + r;
        float ig = sigf(acc[0][r] + b_i);
        float fg = sigf(acc[1][r] + b_f);
        float gg = tanh_f(acc[2][r] + b_g);
        float og = sigf(acc[3][r] + b_o);
        size_t cidx = (size_t)brow * H_ + jglob;
        float cnew = fg * c_buf[cidx] + ig * gg;
        c_buf[cidx] = cnew;
        float hnew = og * tanh_f(cnew);
        h_out[cidx] = f2bf(hnew);
        if (x_index[brow] == t) hn[cidx] = hnew;
    }
}

// ---------------- tail ----------------

__global__ void hn_convert(const float* __restrict__ hn, u16* __restrict__ hnbf) {
    int i = blockIdx.x * 256 + threadIdx.x;  // [0, B*H)
    hnbf[i] = f2bf(hn[i]);
}

// z = tanh(hn @ fc1_w^T + b); grid (16, 4), 64x64 tile, K=1024
__global__ __launch_bounds__(256) void fc1_kernel(
    const u16* __restrict__ A, const u16* __restrict__ Bw,
    const float* __restrict__ bvec, float* __restrict__ z)
{
    __shared__ __align__(16) u16 Al[64 * 72];
    __shared__ __align__(16) u16 Bl[64 * 72];
    const int tid = threadIdx.x;
    const int rowbase = blockIdx.y * 64;
    const int colbase = blockIdx.x * 64;
    floatx4 acc[4] = {{0,0,0,0},{0,0,0,0},{0,0,0,0},{0,0,0,0}};
    const int w = tid >> 6, lane = tid & 63, lr = lane & 15, lk = lane >> 4;

    for (int s = 0; s < H_ / 64; ++s) {
        int k0 = s * 64;
        #pragma unroll
        for (int cc = 0; cc < 2; ++cc) {
            int c = tid + cc * 256;
            int row = c >> 3, kg = c & 7, kglob = k0 + kg * 8;
            *(uint4*)&Al[(row * 9 + kg) * 8] =
                *(const uint4*)(A + (size_t)(rowbase + row) * H_ + kglob);
            *(uint4*)&Bl[(row * 9 + kg) * 8] =
                *(const uint4*)(Bw + (size_t)(colbase + row) * H_ + kglob);
        }
        __syncthreads();
        #pragma unroll
        for (int ks = 0; ks < 2; ++ks) {
            short8 a = *(const short8*)&Al[((16 * w + lr) * 9 + ks * 4 + lk) * 8];
            #pragma unroll
            for (int q = 0; q < 4; ++q) {
                short8 b = *(const short8*)&Bl[((q * 16 + lr) * 9 + ks * 4 + lk) * 8];
                acc[q] = __builtin_amdgcn_mfma_f32_16x16x32_bf16(a, b, acc[q], 0, 0, 0);
            }
        }
        __syncthreads();
    }
    #pragma unroll
    for (int q = 0; q < 4; ++q) {
        int col = colbase + q * 16 + lr;
        float bb = bvec[col];
        #pragma unroll
        for (int r = 0; r < 4; ++r) {
            int row = rowbase + 16 * w + lk * 4 + r;
            z[(size_t)row * M_ + col] = tanh_f(acc[q][r] + bb);
        }
    }
}

// logits + log_softmax over O=2; one wave per batch row
__global__ __launch_bounds__(64) void fc2_softmax(
    const float* __restrict__ z, const float* __restrict__ wmat,
    const float* __restrict__ bvec, float* __restrict__ out)
{
    int bi = blockIdx.x;
    int lane = threadIdx.x;
    const float4* zr = (const float4*)(z + (size_t)bi * M_);
    const float4* w0 = (const float4*)(wmat);
    const float4* w1 = (const float4*)(wmat + M_);
    float s0 = 0.f, s1 = 0.f;
    for (int k = lane; k < M_ / 4; k += 64) {
        float4 zv = zr[k]; float4 a = w0[k]; float4 c = w1[k];
        s0 += zv.x * a.x + zv.y * a.y + zv.z * a.z + zv.w * a.w;
        s1 += zv.x * c.x + zv.y * c.y + zv.z * c.z + zv.w * c.w;
    }
    for (int off = 32; off; off >>= 1) {
        s0 += __shfl_down(s0, off);
        s1 += __shfl_down(s1, off);
    }
    if (lane == 0) {
        float l0 = s0 + bvec[0], l1 = s1 + bvec[1];
        float m = fmaxf(l0, l1);
        float lse = m + __logf(__expf(l0 - m) + __expf(l1 - m));
        out[bi * 2 + 0] = l0 - lse;
        out[bi * 2 + 1] = l1 - lse;
    }
}

// ---------------- launch ----------------

extern "C" void kernel_launch(void* const* d_in, const int* in_sizes, int n_in,
                              void* d_out, int out_size, void* d_ws, size_t ws_size,
                              hipStream_t stream)
{
    const int*   x       = (const int*)  d_in[0];
    const int*   x_index = (const int*)  d_in[1];
    const float* emb_t   = (const float*)d_in[2];
    const float* W_ih    = (const float*)d_in[3];
    const float* W_hh    = (const float*)d_in[4];
    const float* b_ih    = (const float*)d_in[5];
    const float* b_hh    = (const float*)d_in[6];
    const float* fc1_w   = (const float*)d_in[7];
    const float* fc1_b   = (const float*)d_in[8];
    const float* fc2_w   = (const float*)d_in[9];
    const float* fc2_b   = (const float*)d_in[10];
    const float* h0      = (const float*)d_in[11];
    const float* c0      = (const float*)d_in[12];
    float* out = (float*)d_out;

    char* p = (char*)d_ws;
    u16*   emb_bf = (u16*)p;   p += (size_t)B_ * T_ * E_ * 2;   // 134 MB
    u16*   wcat   = (u16*)p;   p += (size_t)G4H * KCAT * 2;     // 12.6 MB
    u16*   fc1wbf = (u16*)p;   p += (size_t)M_ * H_ * 2;        // 2 MB
    float* bias   = (float*)p; p += (size_t)G4H * 4;
    u16*   hb0    = (u16*)p;   p += (size_t)B_ * H_ * 2;
    u16*   hb1    = (u16*)p;   p += (size_t)B_ * H_ * 2;
    float* cbuf   = (float*)p; p += (size_t)B_ * H_ * 4;
    float* hn     = (float*)p; p += (size_t)B_ * H_ * 4;
    u16*   hnbf   = (u16*)p;   p += (size_t)B_ * H_ * 2;
    float* zbuf   = (float*)p; p += (size_t)B_ * M_ * 4;

    prep_emb  <<<65536, 256, 0, stream>>>(x, emb_t, emb_bf);
    prep_wcat <<<6144,  256, 0, stream>>>(W_hh, W_ih, wcat);
    prep_fc1w <<<1024,  256, 0, stream>>>(fc1_w, fc1wbf);
    prep_bias <<<16,    256, 0, stream>>>(b_ih, b_hh, bias);
    prep_state<<<1024,  256, 0, stream>>>(h0, c0, hb0, cbuf);

    for (int t = 0; t < T_; ++t) {
        const u16* hin = (t & 1) ? hb1 : hb0;
        u16* hout      = (t & 1) ? hb0 : hb1;
        lstm_step<<<dim3(64, 4), 256, 0, stream>>>(hin, hout, cbuf, emb_bf, wcat,
                                                   bias, x_index, hn, t);
    }

    hn_convert <<<1024, 256, 0, stream>>>(hn, hnbf);
    fc1_kernel <<<dim3(16, 4), 256, 0, stream>>>(hnbf, fc1wbf, fc1_b, zbuf);
    fc2_softmax<<<256, 64, 0, stream>>>(zbuf, fc2_w, fc2_b, out);
}